// Round 11
// baseline (489.385 us; speedup 1.0000x reference)
//
#include <hip/hip_runtime.h>
#include <hip/hip_bf16.h>

// GCN: 3x GCNConv(relu) -> mean over layers -> global mean pool -> linear -> softmax
// N=100000, E=3200000, F_IN=128, F_HID=64, F_OUT=10, G=1000.
//
// out[dst] = dinv[dst] * ( sum_{e: row[e]=dst} z[col[e]] + z[dst] ) + b,
// z = (x @ W) * dinv[:,None], dinv = rsqrt(deg_col + 1).
//
// R11: aggregate is concurrency-limited (3.1 TB/s vs L3-resident Z, VALUBusy
// 28%): (1) paired-edge gather — lane loads uint (2 bf16), half-wave per edge,
// one instruction = 2 edges = 2 x 128B lines in flight; halves combined via
// shfl_xor(32). (2) aggregate 512-thr blocks. (3) bin_edges 128 blocks
// (bucket-tail chunks 2x bigger -> less partial-line write amp).

#define ALIGN_UP(x, a) (((x) + (a) - 1) / (a) * (a))
#define NBMAX 256        // max buckets (node id >> 9), supports n <= 131072

__device__ __forceinline__ float bf16_to_f32(unsigned short u) {
    return __uint_as_float(((unsigned)u) << 16);
}
__device__ __forceinline__ float bf16_lo(unsigned u) {
    return __uint_as_float(u << 16);
}
__device__ __forceinline__ float bf16_hi(unsigned u) {
    return __uint_as_float(u & 0xffff0000u);
}
__device__ __forceinline__ unsigned pack_bf16(float a, float b) {
    union { __hip_bfloat16 h; unsigned short u; } ua, ub;
    ua.h = __float2bfloat16(a); ub.h = __float2bfloat16(b);
    return (unsigned)ua.u | ((unsigned)ub.u << 16);
}

// ---------------- Pass A: bin edges into 512-node buckets ----------------
// RB entry = (col<<9)|(row&511); CB entry = ushort col&511.
__global__ __launch_bounds__(1024) void bin_edges(const int* __restrict__ row,
                                                  const int* __restrict__ col, int E, int NB, int bcap,
                                                  int* __restrict__ fillR, int* __restrict__ fillC,
                                                  unsigned int* __restrict__ RB,
                                                  unsigned short* __restrict__ CB) {
    __shared__ int cR[NBMAX], cC[NBMAX], bR[NBMAX], bC[NBMAX];
    int t = threadIdx.x;
    for (int i = t; i < NB; i += 1024) { cR[i] = 0; cC[i] = 0; }
    __syncthreads();
    int per = (E + gridDim.x - 1) / gridDim.x;
    int e0 = blockIdx.x * per, e1 = min(E, e0 + per);
    for (int e = e0 + t; e < e1; e += 1024) {
        atomicAdd(&cR[row[e] >> 9], 1);
        atomicAdd(&cC[col[e] >> 9], 1);
    }
    __syncthreads();
    int stag = (int)((blockIdx.x * 37u) % (unsigned)NB);
    for (int j = t; j < NB; j += 1024) {
        int i = j + stag; if (i >= NB) i -= NB;
        bR[i] = cR[i] ? atomicAdd(&fillR[i], cR[i]) : 0;
        bC[i] = cC[i] ? atomicAdd(&fillC[i], cC[i]) : 0;
    }
    __syncthreads();
    for (int i = t; i < NB; i += 1024) { cR[i] = 0; cC[i] = 0; }
    __syncthreads();
    for (int e = e0 + t; e < e1; e += 1024) {    // chunk is L2-hot on re-read
        int r = row[e], c = col[e];
        int br = r >> 9, bc = c >> 9;
        int pR = bR[br] + atomicAdd(&cR[br], 1);
        if (pR < bcap) RB[(size_t)br * bcap + pR] = ((unsigned)c << 9) | ((unsigned)r & 511u);
        int pC = bC[bc] + atomicAdd(&cC[bc], 1);
        if (pC < bcap) CB[(size_t)bc * bcap + pC] = (unsigned short)(c & 511);
    }
}

// ---------------- Pass B: per-bucket CSR build (512 dst/bucket) + dinv ----------------
__global__ __launch_bounds__(1024) void build_csr(const unsigned int* __restrict__ RB,
                                                  const unsigned short* __restrict__ CB,
                                                  const int* __restrict__ fillR,
                                                  const int* __restrict__ fillC,
                                                  int* __restrict__ rowptr, int* __restrict__ indeg,
                                                  float* __restrict__ dinv, int* __restrict__ csr,
                                                  int n, int NB, int E, int bcap) {
    __shared__ int cnt[512], start[512], bump[512];
    __shared__ int wsum[8];
    __shared__ int s_base;
    int b = blockIdx.x, t = threadIdx.x;
    int node0 = b << 9;

    // inline exclusive prefix of bucket totals (wave 0)
    if (t < 64) {
        int pre = 0;
        for (int j = t; j < b; j += 64) pre += min(fillR[j], bcap);
        #pragma unroll
        for (int off = 32; off; off >>= 1) pre += __shfl_down(pre, off, 64);
        if (t == 0) s_base = pre;
    }
    for (int i = t; i < 512; i += 1024) { cnt[i] = 0; bump[i] = 0; }
    __syncthreads();

    int m = min(fillR[b], bcap);
    const unsigned int* src = RB + (size_t)b * bcap;
    for (int i = t; i < m; i += 1024)
        atomicAdd(&cnt[src[i] & 511u], 1);
    __syncthreads();

    // exclusive scan over 512 counters (threads t<512)
    int my = (t < 512) ? cnt[t] : 0;
    int lane = t & 63, w = t >> 6;              // w in 0..7 for t<512
    int x = my;
    #pragma unroll
    for (int off = 1; off < 64; off <<= 1) {
        int y = __shfl_up(x, off, 64);
        if (lane >= off) x += y;
    }
    if (t < 512 && lane == 63) wsum[w] = x;
    __syncthreads();
    int base = s_base;
    if (t < 512) {
        int wb = 0;
        #pragma unroll
        for (int i = 0; i < 8; i++) if (i < w) wb += wsum[i];
        int excl = wb + x - my;
        start[t] = excl;
        int v = node0 + t;
        if (v < n) { rowptr[v] = base + excl; indeg[v] = my; }
    }
    __syncthreads();
    for (int i = t; i < m; i += 1024) {
        unsigned en = src[i];
        int local = (int)(en & 511u);
        int c = (int)(en >> 9);
        int pos = base + start[local] + atomicAdd(&bump[local], 1);
        if (pos < E) csr[pos] = c;              // hardening: never write OOB
    }
    // col-side histogram -> dinv
    __syncthreads();
    for (int i = t; i < 512; i += 1024) cnt[i] = 0;
    __syncthreads();
    int mc = min(fillC[b], bcap);
    const unsigned short* sc = CB + (size_t)b * bcap;
    for (int i = t; i < mc; i += 1024)
        atomicAdd(&cnt[(int)sc[i] & 511], 1);
    __syncthreads();
    int v = node0 + t;
    if (t < 512 && v < n) dinv[v] = rsqrtf((float)(cnt[t] + 1));
}

// ---------------- dense: Z(bf16) = (X @ W) * dinv[:,None] ----------------
// Block = 64 nodes x 64 outputs. lane = node; wave w owns outputs [16w,16w+16).
// W rows are wave-uniform -> scalar s_load. Input f32 (conv1) or bf16 (conv2/3).
template <int K, bool BIN>
__global__ __launch_bounds__(256) void gemm_scale(const void* __restrict__ Xv,
                                                  const float* __restrict__ W,
                                                  const float* __restrict__ dinv,
                                                  unsigned* __restrict__ Z, int n) {
    constexpr int KP = K + 4;                      // row stride (floats), 16B-aligned
    __shared__ __align__(16) float xs[64 * KP];
    int v0 = blockIdx.x * 64;
    int t = threadIdx.x;

    if (BIN) {
        const unsigned* Xu = (const unsigned*)Xv;  // bf16-packed rows of K/2 uints
        constexpr int C8 = K / 8;                  // uint4 chunks per row
        for (int idx = t; idx < 64 * C8; idx += 256) {
            int i = idx / C8, c = idx % C8;
            int v = v0 + i;
            uint4 u = (v < n) ? ((const uint4*)(Xu + (size_t)v * (K / 2)))[c]
                              : make_uint4(0, 0, 0, 0);
            float4 f0, f1;
            f0.x = bf16_lo(u.x); f0.y = bf16_hi(u.x); f0.z = bf16_lo(u.y); f0.w = bf16_hi(u.y);
            f1.x = bf16_lo(u.z); f1.y = bf16_hi(u.z); f1.z = bf16_lo(u.w); f1.w = bf16_hi(u.w);
            *(float4*)&xs[i * KP + c * 8] = f0;
            *(float4*)&xs[i * KP + c * 8 + 4] = f1;
        }
    } else {
        const float* X = (const float*)Xv;
        constexpr int C4 = K / 4;
        for (int idx = t; idx < 64 * C4; idx += 256) {
            int i = idx / C4, c = idx % C4;
            int v = v0 + i;
            float4 val = (v < n) ? ((const float4*)(X + (size_t)v * K))[c]
                                 : make_float4(0.f, 0.f, 0.f, 0.f);
            *(float4*)&xs[i * KP + c * 4] = val;
        }
    }
    __syncthreads();

    int lane = t & 63;
    int wave = __builtin_amdgcn_readfirstlane(t >> 6);
    int j0 = wave * 16;
    float acc[16];
    #pragma unroll
    for (int jj = 0; jj < 16; jj++) acc[jj] = 0.f;

    const float* xrow = &xs[lane * KP];
    #pragma unroll 2
    for (int k = 0; k < K; k += 4) {
        float4 xv = *(const float4*)&xrow[k];
        #pragma unroll
        for (int kk = 0; kk < 4; kk++) {
            float xk = (&xv.x)[kk];
            const float* wrow = W + (k + kk) * 64 + j0;   // wave-uniform -> s_load
            #pragma unroll
            for (int jj = 0; jj < 16; jj++)
                acc[jj] = fmaf(xk, wrow[jj], acc[jj]);
        }
    }

    float dv = (v0 + lane < n) ? dinv[v0 + lane] : 0.f;
    __syncthreads();
    // transpose via LDS (reuse xs) with rotate swizzle; store coalesced bf16 rows
    unsigned* zs32 = (unsigned*)xs;                // 64 nodes x 32 uints (2 bf16 each)
    #pragma unroll
    for (int p = 0; p < 8; p++) {
        int pl = (j0 >> 1) + p;                    // logical uint column
        int phys = (pl + lane) & 31;
        zs32[lane * 32 + phys] = pack_bf16(acc[2 * p] * dv, acc[2 * p + 1] * dv);
    }
    __syncthreads();
    for (int idx = t; idx < 2048; idx += 256) {
        int i = idx >> 5, c = idx & 31;
        int v = v0 + i;
        if (v < n) Z[(size_t)v * 32 + c] = zs32[i * 32 + ((c + i) & 31)];
    }
}

// ---------------- sparse aggregate: paired-edge bf16 gather ----------------
// One wave per dst; lanes 0-31 = even edge, 32-63 = odd edge; each lane loads
// one uint (2 bf16 features). One instruction = 2 edges = 2 x 128B lines.
// Halves combined via shfl_xor(32). csr reads are wave-uniform s_loads.
__global__ __launch_bounds__(512) void aggregate(const unsigned* __restrict__ Zu,
                                                 const int* __restrict__ rowptr,
                                                 const int* __restrict__ indeg,
                                                 const int* __restrict__ csr,
                                                 const float* __restrict__ dinv,
                                                 const float* __restrict__ bias,
                                                 unsigned* __restrict__ Xout, int n) {
    int wave = threadIdx.x >> 6;
    int lane = threadIdx.x & 63;
    int v = blockIdx.x * 8 + wave;
    if (v >= n) return;
    int vs = __builtin_amdgcn_readfirstlane(v);
    int nm1 = n - 1;
    int j = lane & 31;               // uint column (features 2j, 2j+1)
    int hi = lane >> 5;              // 0: even edges, 1: odd edges

    float a0 = 0.f, a1 = 0.f;
    int s = rowptr[vs], c = indeg[vs];
    int i = 0;
    for (; i + 15 < c; i += 16) {                  // 8 paired loads = 16 edges
        unsigned u[8];
        #pragma unroll
        for (int p = 0; p < 8; p++) {
            int e0 = min(csr[s + i + 2 * p], nm1);       // s_load (uniform)
            int e1 = min(csr[s + i + 2 * p + 1], nm1);
            int sel = hi ? e1 : e0;
            u[p] = Zu[(size_t)sel * 32 + j];
        }
        #pragma unroll
        for (int p = 0; p < 8; p++) { a0 += bf16_lo(u[p]); a1 += bf16_hi(u[p]); }
    }
    for (; i + 1 < c; i += 2) {
        int e0 = min(csr[s + i], nm1);
        int e1 = min(csr[s + i + 1], nm1);
        int sel = hi ? e1 : e0;
        unsigned u = Zu[(size_t)sel * 32 + j];
        a0 += bf16_lo(u); a1 += bf16_hi(u);
    }
    if (i < c && hi == 0) {                        // odd tail: low half only
        unsigned u = Zu[(size_t)min(csr[s + i], nm1) * 32 + j];
        a0 += bf16_lo(u); a1 += bf16_hi(u);
    }
    // combine even/odd halves
    a0 += __shfl_xor(a0, 32, 64);
    a1 += __shfl_xor(a1, 32, 64);
    // self-loop (after combine: added exactly once per lane)
    unsigned us = Zu[(size_t)vs * 32 + j];
    a0 += bf16_lo(us); a1 += bf16_hi(us);

    float dv = dinv[vs];
    float2 bb = ((const float2*)bias)[j];
    float f0 = fmaxf(a0 * dv + bb.x, 0.f);
    float f1 = fmaxf(a1 * dv + bb.y, 0.f);
    if (hi == 0)
        Xout[(size_t)vs * 32 + j] = pack_bf16(f0, f1);
}

// ---------------- fused pool (block per graph, batch sorted) + linear + softmax ----------------
__device__ __forceinline__ int lbound(const int* a, int n, int key) {
    int lo = 0, hi = n;
    while (lo < hi) { int mid = (lo + hi) >> 1; if (a[mid] < key) lo = mid + 1; else hi = mid; }
    return lo;
}

__global__ __launch_bounds__(256) void pool_head(const unsigned short* __restrict__ x1,
                                                 const unsigned short* __restrict__ x2,
                                                 const unsigned short* __restrict__ x3,
                                                 const int* __restrict__ batch,
                                                 const float* __restrict__ Wl,
                                                 const float* __restrict__ bl,
                                                 float* __restrict__ out, int n) {
    __shared__ int sb[2];
    __shared__ float red[4][64];
    __shared__ float ps[64];
    __shared__ float lg[10];
    int g = blockIdx.x, t = threadIdx.x;
    int wave = t >> 6, lane = t & 63;
    if (t < 2) sb[t] = lbound(batch, n, g + t);
    __syncthreads();
    int s0 = sb[0], s1 = sb[1];
    float acc = 0.f;
    for (int v = s0 + wave; v < s1; v += 4)
        acc += bf16_to_f32(x1[(size_t)v * 64 + lane])
             + bf16_to_f32(x2[(size_t)v * 64 + lane])
             + bf16_to_f32(x3[(size_t)v * 64 + lane]);
    red[wave][lane] = acc;
    __syncthreads();
    if (t < 64) {
        int c = s1 - s0;
        float denom = 3.0f * (float)(c > 1 ? c : 1);
        ps[t] = (red[0][t] + red[1][t] + red[2][t] + red[3][t]) / denom;
    }
    __syncthreads();
    if (t < 10) {
        float a = bl[t];
        #pragma unroll 8
        for (int f = 0; f < 64; f++) a += ps[f] * Wl[f * 10 + t];
        lg[t] = a;
    }
    __syncthreads();
    if (t < 10) {
        float mx = -1e30f;
        for (int j = 0; j < 10; j++) mx = fmaxf(mx, lg[j]);
        float e = expf(lg[t] - mx);
        float ss = 0.f;
        for (int j = 0; j < 10; j++) ss += expf(lg[j] - mx);
        out[g * 10 + t] = e / ss;
    }
}

extern "C" void kernel_launch(void* const* d_in, const int* in_sizes, int n_in,
                              void* d_out, int out_size, void* d_ws, size_t ws_size,
                              hipStream_t stream) {
    const float* feats = (const float*)d_in[0];
    const int*   eidx  = (const int*)d_in[1];
    const int*   batch = (const int*)d_in[2];
    const float* W1 = (const float*)d_in[4];
    const float* b1 = (const float*)d_in[5];
    const float* W2 = (const float*)d_in[6];
    const float* b2 = (const float*)d_in[7];
    const float* W3 = (const float*)d_in[8];
    const float* b3 = (const float*)d_in[9];
    const float* Wl = (const float*)d_in[10];
    const float* bl = (const float*)d_in[11];
    float* out = (float*)d_out;

    int n = in_sizes[0] / 128;
    int E = in_sizes[1] / 2;
    int G = out_size / 10;
    int NB = ((n - 1) >> 9) + 1;                   // 512-node buckets
    int per = E / NB;
    int bcap = ALIGN_UP(per + per / 8 + 512, 64);  // mean + >15 sigma margin
    const int* row = eidx;       // destination
    const int* col = eidx + E;   // source

    char* ws = (char*)d_ws;
    size_t o = 0;
    size_t o_fill   = o; o += 2 * NBMAX * 4;                         // fillR | fillC (zeroed)
    size_t o_rowptr = o; o += ALIGN_UP((size_t)n * 4, 256);
    size_t o_indeg  = o; o += ALIGN_UP((size_t)n * 4, 256);
    size_t o_dinv   = o; o += ALIGN_UP((size_t)n * 4, 256);
    size_t o_csr    = o; o += ALIGN_UP((size_t)E * 4, 256);
    size_t o_z      = o; o += ALIGN_UP((size_t)n * 64 * 2, 256);     // bf16 Z
    size_t o_union  = o;                                             // RB+CB | x1..x3
    size_t rb_bytes = ALIGN_UP((size_t)NB * bcap * 4, 256);
    size_t xl_bytes = ALIGN_UP((size_t)n * 64 * 2, 256);             // bf16 x-layers
    (void)ws_size; (void)n_in;

    int*   fillR = (int*)(ws + o_fill);
    int*   fillC = fillR + NBMAX;
    int*   rowptr = (int*)(ws + o_rowptr);
    int*   indeg  = (int*)(ws + o_indeg);
    float* dinv   = (float*)(ws + o_dinv);
    int*   csr    = (int*)(ws + o_csr);
    unsigned* z   = (unsigned*)(ws + o_z);
    unsigned int*   RB = (unsigned int*)(ws + o_union);
    unsigned short* CB = (unsigned short*)(ws + o_union + rb_bytes);
    unsigned* x1 = (unsigned*)(ws + o_union);
    unsigned* x2 = (unsigned*)(ws + o_union + xl_bytes);
    unsigned* x3 = (unsigned*)(ws + o_union + 2 * xl_bytes);

    hipMemsetAsync(ws + o_fill, 0, 2 * NBMAX * 4, stream);

    int gridG = (n + 63) / 64;   // gemm: 64 nodes per block
    int gridA = (n + 7) / 8;     // aggregate: 8 waves/block, one node per wave

    bin_edges<<<128, 1024, 0, stream>>>(row, col, E, NB, bcap, fillR, fillC, RB, CB);
    build_csr<<<NB, 1024, 0, stream>>>(RB, CB, fillR, fillC,
                                       rowptr, indeg, dinv, csr, n, NB, E, bcap);

    // conv1 (RB/CB dead after build_csr; x1 overlays them)
    gemm_scale<128, false><<<gridG, 256, 0, stream>>>(feats, W1, dinv, z, n);
    aggregate<<<gridA, 512, 0, stream>>>(z, rowptr, indeg, csr, dinv, b1, x1, n);
    // conv2
    gemm_scale<64, true><<<gridG, 256, 0, stream>>>(x1, W2, dinv, z, n);
    aggregate<<<gridA, 512, 0, stream>>>(z, rowptr, indeg, csr, dinv, b2, x2, n);
    // conv3
    gemm_scale<64, true><<<gridG, 256, 0, stream>>>(x2, W3, dinv, z, n);
    aggregate<<<gridA, 512, 0, stream>>>(z, rowptr, indeg, csr, dinv, b3, x3, n);

    pool_head<<<G, 256, 0, stream>>>((const unsigned short*)x1, (const unsigned short*)x2,
                                     (const unsigned short*)x3, batch, Wl, bl, out, n);
}

// Round 12
// 466.015 us; speedup vs baseline: 1.0501x; 1.0501x over previous
//
#include <hip/hip_runtime.h>
#include <hip/hip_bf16.h>

// GCN: 3x GCNConv(relu) -> mean over layers -> global mean pool -> linear -> softmax
// N=100000, E=3200000, F_IN=128, F_HID=64, F_OUT=10, G=1000.
//
// out[dst] = dinv[dst] * ( sum_{e: row[e]=dst} z[col[e]] + z[dst] ) + b,
// z = (x @ W) * dinv[:,None], dinv = rsqrt(deg_col + 1).
//
// R12: R11's bin_edges at 128 blocks starved the machine (0.5 block/CU,
// occupancy 19%, 70us). Single fix: bin_edges back to 256 blocks (1/CU).
// Paired-edge aggregate kept (neutral-to-better vs R10's 58.6us).

#define ALIGN_UP(x, a) (((x) + (a) - 1) / (a) * (a))
#define NBMAX 256        // max buckets (node id >> 9), supports n <= 131072

__device__ __forceinline__ float bf16_to_f32(unsigned short u) {
    return __uint_as_float(((unsigned)u) << 16);
}
__device__ __forceinline__ float bf16_lo(unsigned u) {
    return __uint_as_float(u << 16);
}
__device__ __forceinline__ float bf16_hi(unsigned u) {
    return __uint_as_float(u & 0xffff0000u);
}
__device__ __forceinline__ unsigned pack_bf16(float a, float b) {
    union { __hip_bfloat16 h; unsigned short u; } ua, ub;
    ua.h = __float2bfloat16(a); ub.h = __float2bfloat16(b);
    return (unsigned)ua.u | ((unsigned)ub.u << 16);
}

// ---------------- Pass A: bin edges into 512-node buckets ----------------
// RB entry = (col<<9)|(row&511); CB entry = ushort col&511.
__global__ __launch_bounds__(1024) void bin_edges(const int* __restrict__ row,
                                                  const int* __restrict__ col, int E, int NB, int bcap,
                                                  int* __restrict__ fillR, int* __restrict__ fillC,
                                                  unsigned int* __restrict__ RB,
                                                  unsigned short* __restrict__ CB) {
    __shared__ int cR[NBMAX], cC[NBMAX], bR[NBMAX], bC[NBMAX];
    int t = threadIdx.x;
    for (int i = t; i < NB; i += 1024) { cR[i] = 0; cC[i] = 0; }
    __syncthreads();
    int per = (E + gridDim.x - 1) / gridDim.x;
    int e0 = blockIdx.x * per, e1 = min(E, e0 + per);
    for (int e = e0 + t; e < e1; e += 1024) {
        atomicAdd(&cR[row[e] >> 9], 1);
        atomicAdd(&cC[col[e] >> 9], 1);
    }
    __syncthreads();
    int stag = (int)((blockIdx.x * 37u) % (unsigned)NB);
    for (int j = t; j < NB; j += 1024) {
        int i = j + stag; if (i >= NB) i -= NB;
        bR[i] = cR[i] ? atomicAdd(&fillR[i], cR[i]) : 0;
        bC[i] = cC[i] ? atomicAdd(&fillC[i], cC[i]) : 0;
    }
    __syncthreads();
    for (int i = t; i < NB; i += 1024) { cR[i] = 0; cC[i] = 0; }
    __syncthreads();
    for (int e = e0 + t; e < e1; e += 1024) {    // chunk is L2-hot on re-read
        int r = row[e], c = col[e];
        int br = r >> 9, bc = c >> 9;
        int pR = bR[br] + atomicAdd(&cR[br], 1);
        if (pR < bcap) RB[(size_t)br * bcap + pR] = ((unsigned)c << 9) | ((unsigned)r & 511u);
        int pC = bC[bc] + atomicAdd(&cC[bc], 1);
        if (pC < bcap) CB[(size_t)bc * bcap + pC] = (unsigned short)(c & 511);
    }
}

// ---------------- Pass B: per-bucket CSR build (512 dst/bucket) + dinv ----------------
__global__ __launch_bounds__(1024) void build_csr(const unsigned int* __restrict__ RB,
                                                  const unsigned short* __restrict__ CB,
                                                  const int* __restrict__ fillR,
                                                  const int* __restrict__ fillC,
                                                  int* __restrict__ rowptr, int* __restrict__ indeg,
                                                  float* __restrict__ dinv, int* __restrict__ csr,
                                                  int n, int NB, int E, int bcap) {
    __shared__ int cnt[512], start[512], bump[512];
    __shared__ int wsum[8];
    __shared__ int s_base;
    int b = blockIdx.x, t = threadIdx.x;
    int node0 = b << 9;

    // inline exclusive prefix of bucket totals (wave 0)
    if (t < 64) {
        int pre = 0;
        for (int j = t; j < b; j += 64) pre += min(fillR[j], bcap);
        #pragma unroll
        for (int off = 32; off; off >>= 1) pre += __shfl_down(pre, off, 64);
        if (t == 0) s_base = pre;
    }
    for (int i = t; i < 512; i += 1024) { cnt[i] = 0; bump[i] = 0; }
    __syncthreads();

    int m = min(fillR[b], bcap);
    const unsigned int* src = RB + (size_t)b * bcap;
    for (int i = t; i < m; i += 1024)
        atomicAdd(&cnt[src[i] & 511u], 1);
    __syncthreads();

    // exclusive scan over 512 counters (threads t<512)
    int my = (t < 512) ? cnt[t] : 0;
    int lane = t & 63, w = t >> 6;              // w in 0..7 for t<512
    int x = my;
    #pragma unroll
    for (int off = 1; off < 64; off <<= 1) {
        int y = __shfl_up(x, off, 64);
        if (lane >= off) x += y;
    }
    if (t < 512 && lane == 63) wsum[w] = x;
    __syncthreads();
    int base = s_base;
    if (t < 512) {
        int wb = 0;
        #pragma unroll
        for (int i = 0; i < 8; i++) if (i < w) wb += wsum[i];
        int excl = wb + x - my;
        start[t] = excl;
        int v = node0 + t;
        if (v < n) { rowptr[v] = base + excl; indeg[v] = my; }
    }
    __syncthreads();
    for (int i = t; i < m; i += 1024) {
        unsigned en = src[i];
        int local = (int)(en & 511u);
        int c = (int)(en >> 9);
        int pos = base + start[local] + atomicAdd(&bump[local], 1);
        if (pos < E) csr[pos] = c;              // hardening: never write OOB
    }
    // col-side histogram -> dinv
    __syncthreads();
    for (int i = t; i < 512; i += 1024) cnt[i] = 0;
    __syncthreads();
    int mc = min(fillC[b], bcap);
    const unsigned short* sc = CB + (size_t)b * bcap;
    for (int i = t; i < mc; i += 1024)
        atomicAdd(&cnt[(int)sc[i] & 511], 1);
    __syncthreads();
    int v = node0 + t;
    if (t < 512 && v < n) dinv[v] = rsqrtf((float)(cnt[t] + 1));
}

// ---------------- dense: Z(bf16) = (X @ W) * dinv[:,None] ----------------
// Block = 64 nodes x 64 outputs. lane = node; wave w owns outputs [16w,16w+16).
// W rows are wave-uniform -> scalar s_load. Input f32 (conv1) or bf16 (conv2/3).
template <int K, bool BIN>
__global__ __launch_bounds__(256) void gemm_scale(const void* __restrict__ Xv,
                                                  const float* __restrict__ W,
                                                  const float* __restrict__ dinv,
                                                  unsigned* __restrict__ Z, int n) {
    constexpr int KP = K + 4;                      // row stride (floats), 16B-aligned
    __shared__ __align__(16) float xs[64 * KP];
    int v0 = blockIdx.x * 64;
    int t = threadIdx.x;

    if (BIN) {
        const unsigned* Xu = (const unsigned*)Xv;  // bf16-packed rows of K/2 uints
        constexpr int C8 = K / 8;                  // uint4 chunks per row
        for (int idx = t; idx < 64 * C8; idx += 256) {
            int i = idx / C8, c = idx % C8;
            int v = v0 + i;
            uint4 u = (v < n) ? ((const uint4*)(Xu + (size_t)v * (K / 2)))[c]
                              : make_uint4(0, 0, 0, 0);
            float4 f0, f1;
            f0.x = bf16_lo(u.x); f0.y = bf16_hi(u.x); f0.z = bf16_lo(u.y); f0.w = bf16_hi(u.y);
            f1.x = bf16_lo(u.z); f1.y = bf16_hi(u.z); f1.z = bf16_lo(u.w); f1.w = bf16_hi(u.w);
            *(float4*)&xs[i * KP + c * 8] = f0;
            *(float4*)&xs[i * KP + c * 8 + 4] = f1;
        }
    } else {
        const float* X = (const float*)Xv;
        constexpr int C4 = K / 4;
        for (int idx = t; idx < 64 * C4; idx += 256) {
            int i = idx / C4, c = idx % C4;
            int v = v0 + i;
            float4 val = (v < n) ? ((const float4*)(X + (size_t)v * K))[c]
                                 : make_float4(0.f, 0.f, 0.f, 0.f);
            *(float4*)&xs[i * KP + c * 4] = val;
        }
    }
    __syncthreads();

    int lane = t & 63;
    int wave = __builtin_amdgcn_readfirstlane(t >> 6);
    int j0 = wave * 16;
    float acc[16];
    #pragma unroll
    for (int jj = 0; jj < 16; jj++) acc[jj] = 0.f;

    const float* xrow = &xs[lane * KP];
    #pragma unroll 2
    for (int k = 0; k < K; k += 4) {
        float4 xv = *(const float4*)&xrow[k];
        #pragma unroll
        for (int kk = 0; kk < 4; kk++) {
            float xk = (&xv.x)[kk];
            const float* wrow = W + (k + kk) * 64 + j0;   // wave-uniform -> s_load
            #pragma unroll
            for (int jj = 0; jj < 16; jj++)
                acc[jj] = fmaf(xk, wrow[jj], acc[jj]);
        }
    }

    float dv = (v0 + lane < n) ? dinv[v0 + lane] : 0.f;
    __syncthreads();
    // transpose via LDS (reuse xs) with rotate swizzle; store coalesced bf16 rows
    unsigned* zs32 = (unsigned*)xs;                // 64 nodes x 32 uints (2 bf16 each)
    #pragma unroll
    for (int p = 0; p < 8; p++) {
        int pl = (j0 >> 1) + p;                    // logical uint column
        int phys = (pl + lane) & 31;
        zs32[lane * 32 + phys] = pack_bf16(acc[2 * p] * dv, acc[2 * p + 1] * dv);
    }
    __syncthreads();
    for (int idx = t; idx < 2048; idx += 256) {
        int i = idx >> 5, c = idx & 31;
        int v = v0 + i;
        if (v < n) Z[(size_t)v * 32 + c] = zs32[i * 32 + ((c + i) & 31)];
    }
}

// ---------------- sparse aggregate: paired-edge bf16 gather ----------------
// One wave per dst; lanes 0-31 = even edge, 32-63 = odd edge; each lane loads
// one uint (2 bf16 features). One instruction = 2 edges = 2 x 128B lines.
// Halves combined via shfl_xor(32). csr reads are wave-uniform s_loads.
__global__ __launch_bounds__(512) void aggregate(const unsigned* __restrict__ Zu,
                                                 const int* __restrict__ rowptr,
                                                 const int* __restrict__ indeg,
                                                 const int* __restrict__ csr,
                                                 const float* __restrict__ dinv,
                                                 const float* __restrict__ bias,
                                                 unsigned* __restrict__ Xout, int n) {
    int wave = threadIdx.x >> 6;
    int lane = threadIdx.x & 63;
    int v = blockIdx.x * 8 + wave;
    if (v >= n) return;
    int vs = __builtin_amdgcn_readfirstlane(v);
    int nm1 = n - 1;
    int j = lane & 31;               // uint column (features 2j, 2j+1)
    int hi = lane >> 5;              // 0: even edges, 1: odd edges

    float a0 = 0.f, a1 = 0.f;
    int s = rowptr[vs], c = indeg[vs];
    int i = 0;
    for (; i + 15 < c; i += 16) {                  // 8 paired loads = 16 edges
        unsigned u[8];
        #pragma unroll
        for (int p = 0; p < 8; p++) {
            int e0 = min(csr[s + i + 2 * p], nm1);       // s_load (uniform)
            int e1 = min(csr[s + i + 2 * p + 1], nm1);
            int sel = hi ? e1 : e0;
            u[p] = Zu[(size_t)sel * 32 + j];
        }
        #pragma unroll
        for (int p = 0; p < 8; p++) { a0 += bf16_lo(u[p]); a1 += bf16_hi(u[p]); }
    }
    for (; i + 1 < c; i += 2) {
        int e0 = min(csr[s + i], nm1);
        int e1 = min(csr[s + i + 1], nm1);
        int sel = hi ? e1 : e0;
        unsigned u = Zu[(size_t)sel * 32 + j];
        a0 += bf16_lo(u); a1 += bf16_hi(u);
    }
    if (i < c && hi == 0) {                        // odd tail: low half only
        unsigned u = Zu[(size_t)min(csr[s + i], nm1) * 32 + j];
        a0 += bf16_lo(u); a1 += bf16_hi(u);
    }
    // combine even/odd halves
    a0 += __shfl_xor(a0, 32, 64);
    a1 += __shfl_xor(a1, 32, 64);
    // self-loop (after combine: added exactly once per lane)
    unsigned us = Zu[(size_t)vs * 32 + j];
    a0 += bf16_lo(us); a1 += bf16_hi(us);

    float dv = dinv[vs];
    float2 bb = ((const float2*)bias)[j];
    float f0 = fmaxf(a0 * dv + bb.x, 0.f);
    float f1 = fmaxf(a1 * dv + bb.y, 0.f);
    if (hi == 0)
        Xout[(size_t)vs * 32 + j] = pack_bf16(f0, f1);
}

// ---------------- fused pool (block per graph, batch sorted) + linear + softmax ----------------
__device__ __forceinline__ int lbound(const int* a, int n, int key) {
    int lo = 0, hi = n;
    while (lo < hi) { int mid = (lo + hi) >> 1; if (a[mid] < key) lo = mid + 1; else hi = mid; }
    return lo;
}

__global__ __launch_bounds__(256) void pool_head(const unsigned short* __restrict__ x1,
                                                 const unsigned short* __restrict__ x2,
                                                 const unsigned short* __restrict__ x3,
                                                 const int* __restrict__ batch,
                                                 const float* __restrict__ Wl,
                                                 const float* __restrict__ bl,
                                                 float* __restrict__ out, int n) {
    __shared__ int sb[2];
    __shared__ float red[4][64];
    __shared__ float ps[64];
    __shared__ float lg[10];
    int g = blockIdx.x, t = threadIdx.x;
    int wave = t >> 6, lane = t & 63;
    if (t < 2) sb[t] = lbound(batch, n, g + t);
    __syncthreads();
    int s0 = sb[0], s1 = sb[1];
    float acc = 0.f;
    for (int v = s0 + wave; v < s1; v += 4)
        acc += bf16_to_f32(x1[(size_t)v * 64 + lane])
             + bf16_to_f32(x2[(size_t)v * 64 + lane])
             + bf16_to_f32(x3[(size_t)v * 64 + lane]);
    red[wave][lane] = acc;
    __syncthreads();
    if (t < 64) {
        int c = s1 - s0;
        float denom = 3.0f * (float)(c > 1 ? c : 1);
        ps[t] = (red[0][t] + red[1][t] + red[2][t] + red[3][t]) / denom;
    }
    __syncthreads();
    if (t < 10) {
        float a = bl[t];
        #pragma unroll 8
        for (int f = 0; f < 64; f++) a += ps[f] * Wl[f * 10 + t];
        lg[t] = a;
    }
    __syncthreads();
    if (t < 10) {
        float mx = -1e30f;
        for (int j = 0; j < 10; j++) mx = fmaxf(mx, lg[j]);
        float e = expf(lg[t] - mx);
        float ss = 0.f;
        for (int j = 0; j < 10; j++) ss += expf(lg[j] - mx);
        out[g * 10 + t] = e / ss;
    }
}

extern "C" void kernel_launch(void* const* d_in, const int* in_sizes, int n_in,
                              void* d_out, int out_size, void* d_ws, size_t ws_size,
                              hipStream_t stream) {
    const float* feats = (const float*)d_in[0];
    const int*   eidx  = (const int*)d_in[1];
    const int*   batch = (const int*)d_in[2];
    const float* W1 = (const float*)d_in[4];
    const float* b1 = (const float*)d_in[5];
    const float* W2 = (const float*)d_in[6];
    const float* b2 = (const float*)d_in[7];
    const float* W3 = (const float*)d_in[8];
    const float* b3 = (const float*)d_in[9];
    const float* Wl = (const float*)d_in[10];
    const float* bl = (const float*)d_in[11];
    float* out = (float*)d_out;

    int n = in_sizes[0] / 128;
    int E = in_sizes[1] / 2;
    int G = out_size / 10;
    int NB = ((n - 1) >> 9) + 1;                   // 512-node buckets
    int per = E / NB;
    int bcap = ALIGN_UP(per + per / 8 + 512, 64);  // mean + >15 sigma margin
    const int* row = eidx;       // destination
    const int* col = eidx + E;   // source

    char* ws = (char*)d_ws;
    size_t o = 0;
    size_t o_fill   = o; o += 2 * NBMAX * 4;                         // fillR | fillC (zeroed)
    size_t o_rowptr = o; o += ALIGN_UP((size_t)n * 4, 256);
    size_t o_indeg  = o; o += ALIGN_UP((size_t)n * 4, 256);
    size_t o_dinv   = o; o += ALIGN_UP((size_t)n * 4, 256);
    size_t o_csr    = o; o += ALIGN_UP((size_t)E * 4, 256);
    size_t o_z      = o; o += ALIGN_UP((size_t)n * 64 * 2, 256);     // bf16 Z
    size_t o_union  = o;                                             // RB+CB | x1..x3
    size_t rb_bytes = ALIGN_UP((size_t)NB * bcap * 4, 256);
    size_t xl_bytes = ALIGN_UP((size_t)n * 64 * 2, 256);             // bf16 x-layers
    (void)ws_size; (void)n_in;

    int*   fillR = (int*)(ws + o_fill);
    int*   fillC = fillR + NBMAX;
    int*   rowptr = (int*)(ws + o_rowptr);
    int*   indeg  = (int*)(ws + o_indeg);
    float* dinv   = (float*)(ws + o_dinv);
    int*   csr    = (int*)(ws + o_csr);
    unsigned* z   = (unsigned*)(ws + o_z);
    unsigned int*   RB = (unsigned int*)(ws + o_union);
    unsigned short* CB = (unsigned short*)(ws + o_union + rb_bytes);
    unsigned* x1 = (unsigned*)(ws + o_union);
    unsigned* x2 = (unsigned*)(ws + o_union + xl_bytes);
    unsigned* x3 = (unsigned*)(ws + o_union + 2 * xl_bytes);

    hipMemsetAsync(ws + o_fill, 0, 2 * NBMAX * 4, stream);

    int gridG = (n + 63) / 64;   // gemm: 64 nodes per block
    int gridA = (n + 7) / 8;     // aggregate: 8 waves/block, one node per wave

    bin_edges<<<256, 1024, 0, stream>>>(row, col, E, NB, bcap, fillR, fillC, RB, CB);
    build_csr<<<NB, 1024, 0, stream>>>(RB, CB, fillR, fillC,
                                       rowptr, indeg, dinv, csr, n, NB, E, bcap);

    // conv1 (RB/CB dead after build_csr; x1 overlays them)
    gemm_scale<128, false><<<gridG, 256, 0, stream>>>(feats, W1, dinv, z, n);
    aggregate<<<gridA, 512, 0, stream>>>(z, rowptr, indeg, csr, dinv, b1, x1, n);
    // conv2
    gemm_scale<64, true><<<gridG, 256, 0, stream>>>(x1, W2, dinv, z, n);
    aggregate<<<gridA, 512, 0, stream>>>(z, rowptr, indeg, csr, dinv, b2, x2, n);
    // conv3
    gemm_scale<64, true><<<gridG, 256, 0, stream>>>(x2, W3, dinv, z, n);
    aggregate<<<gridA, 512, 0, stream>>>(z, rowptr, indeg, csr, dinv, b3, x3, n);

    pool_head<<<G, 256, 0, stream>>>((const unsigned short*)x1, (const unsigned short*)x2,
                                     (const unsigned short*)x3, batch, Wl, bl, out, n);
}